// Round 15
// baseline (133.752 us; speedup 1.0000x reference)
//
#include <hip/hip_runtime.h>

#pragma clang fp contract(off)

#define T_CAND 856
#define NW 14          // ceil(856/64)
#define NSH 16         // sub-histograms
#define HSTR 513       // sub-hist stride in words (odd -> banks spread)
#define GB 4096        // gather buffer entries (32 KB; slack-1 worst case ~1740)

__device__ const int d_HW[5]  = {12800, 3200, 800, 208, 56};
__device__ const int d_K[5]   = {200, 200, 200, 200, 56};
__device__ const int d_OFF[5] = {0, 200, 400, 600, 800};

struct LevelPtrs {
  const float* loc[5];
  const float* cls[5];
  const float* reg[5];
  const int*   img;
};

__device__ __forceinline__ unsigned long long readlane64(unsigned long long v, int lane) {
  const unsigned lo = (unsigned)__builtin_amdgcn_readlane((int)(unsigned)(v & 0xFFFFFFFFULL), lane);
  const unsigned hi = (unsigned)__builtin_amdgcn_readlane((int)(unsigned)(v >> 32), lane);
  return ((unsigned long long)hi << 32) | lo;
}
__device__ __forceinline__ unsigned long long rfl64(unsigned long long v) {
  const unsigned lo = (unsigned)__builtin_amdgcn_readfirstlane((int)(unsigned)(v & 0xFFFFFFFFULL));
  const unsigned hi = (unsigned)__builtin_amdgcn_readfirstlane((int)(unsigned)(v >> 32));
  return ((unsigned long long)hi << 32) | lo;
}

// Register-only polygon-clip IoU (bit-identical to validated R9/R12/R13 clip body).
__device__ __forceinline__ bool clip_hit4(float4 a01, float4 a23, float4 b01, float4 b23) {
  const float ax0 = a01.x, ay0 = a01.y, ax1 = a01.z, ay1 = a01.w,
              ax2 = a23.x, ay2 = a23.y, ax3 = a23.z, ay3 = a23.w;
  const float bx0 = b01.x, by0 = b01.y, bx1 = b01.z, by1 = b01.w,
              bx2 = b23.x, by2 = b23.y, bx3 = b23.z, by3 = b23.w;
  float sB = bx0 * by1 - bx1 * by0;
  sB += bx1 * by2 - bx2 * by1;
  sB += bx2 * by3 - bx3 * by2;
  sB += bx3 * by0 - bx0 * by3;
  const float orient = (sB >= 0.0f) ? 1.0f : -1.0f;
  float aA = ax0 * ay1 - ax1 * ay0;
  aA += ax1 * ay2 - ax2 * ay1;
  aA += ax2 * ay3 - ax3 * ay2;
  aA += ax3 * ay0 - ax0 * ay3;

  float s0x = ax0, s0y = ay0, s1x = ax1, s1y = ay1,
        s2x = ax2, s2y = ay2, s3x = ax3, s3y = ay3,
        s4x = 0.f, s4y = 0.f, s5x = 0.f, s5y = 0.f,
        s6x = 0.f, s6y = 0.f, s7x = 0.f, s7y = 0.f;
  int n = 4;
  float lastx = ax3, lasty = ay3;          // V[n-1] of initial polygon
  const float bex[5] = {bx0, bx1, bx2, bx3, bx0};
  const float bey[5] = {by0, by1, by2, by3, by0};

#define PUSH(w_, vx_, vy_)                                              \
  {                                                                     \
    const bool w__ = (w_);                                              \
    const float vx__ = (vx_), vy__ = (vy_);                             \
    t0x = (w__ && cnt == 0) ? vx__ : t0x; t0y = (w__ && cnt == 0) ? vy__ : t0y; \
    t1x = (w__ && cnt == 1) ? vx__ : t1x; t1y = (w__ && cnt == 1) ? vy__ : t1y; \
    t2x = (w__ && cnt == 2) ? vx__ : t2x; t2y = (w__ && cnt == 2) ? vy__ : t2y; \
    t3x = (w__ && cnt == 3) ? vx__ : t3x; t3y = (w__ && cnt == 3) ? vy__ : t3y; \
    t4x = (w__ && cnt == 4) ? vx__ : t4x; t4y = (w__ && cnt == 4) ? vy__ : t4y; \
    t5x = (w__ && cnt == 5) ? vx__ : t5x; t5y = (w__ && cnt == 5) ? vy__ : t5y; \
    t6x = (w__ && cnt == 6) ? vx__ : t6x; t6y = (w__ && cnt == 6) ? vy__ : t6y; \
    t7x = (w__ && cnt == 7) ? vx__ : t7x; t7y = (w__ && cnt == 7) ? vy__ : t7y; \
    nlx = (w__ && cnt < 8) ? vx__ : nlx;  nly = (w__ && cnt < 8) ? vy__ : nly;  \
    cnt += w__ ? 1 : 0;                                                 \
  }

#define CLIP_K(k_, sx_, sy_)                                            \
  {                                                                     \
    const bool act = (k_) < n;                                          \
    const float cx = sx_, cy = sy_;                                     \
    const float sc2 = orient * (dx * (cy - p1y) - dy * (cx - p1x));     \
    const bool cin = (sc2 >= 0.0f), pin = (sp >= 0.0f);                 \
    const float den = sp - sc2;                                         \
    const float dd = (fabsf(den) > 1e-9f) ? den : 1e-9f;                \
    const float tt = sp / dd;                                           \
    const float ipx = px + tt * (cx - px);                              \
    const float ipy = py + tt * (cy - py);                              \
    PUSH(act && (cin != pin), ipx, ipy);                                \
    PUSH(act && cin, cx, cy);                                           \
    px = cx; py = cy; sp = sc2;                                         \
  }

#pragma unroll
  for (int e = 0; e < 4; ++e) {
    const float p1x = bex[e], p1y = bey[e];
    const float dx = bex[e + 1] - p1x, dy = bey[e + 1] - p1y;
    float t0x = 0.f, t0y = 0.f, t1x = 0.f, t1y = 0.f, t2x = 0.f, t2y = 0.f,
          t3x = 0.f, t3y = 0.f, t4x = 0.f, t4y = 0.f, t5x = 0.f, t5y = 0.f,
          t6x = 0.f, t6y = 0.f, t7x = 0.f, t7y = 0.f;
    float nlx = lastx, nly = lasty;
    int cnt = 0;
    float px = lastx, py = lasty;
    float sp = orient * (dx * (py - p1y) - dy * (px - p1x));
    CLIP_K(0, s0x, s0y) CLIP_K(1, s1x, s1y) CLIP_K(2, s2x, s2y) CLIP_K(3, s3x, s3y)
    CLIP_K(4, s4x, s4y) CLIP_K(5, s5x, s5y) CLIP_K(6, s6x, s6y) CLIP_K(7, s7x, s7y)
    s0x = t0x; s0y = t0y; s1x = t1x; s1y = t1y; s2x = t2x; s2y = t2y;
    s3x = t3x; s3y = t3y; s4x = t4x; s4y = t4y; s5x = t5x; s5y = t5y;
    s6x = t6x; s6y = t6y; s7x = t7x; s7y = t7y;
    lastx = nlx; lasty = nly;
    n = cnt;           // raw (may exceed 8) — matches validated semantics
  }
#undef CLIP_K
#undef PUSH

  float a = 0.0f;
#define SHOE(k_, xk_, yk_, xn_, yn_)                                    \
  {                                                                     \
    const bool act = (k_) < n;                                          \
    const bool wrap = (k_) == n - 1;                                    \
    const float xn = wrap ? s0x : (xn_);                                \
    const float yn = wrap ? s0y : (yn_);                                \
    const float term = (xk_) * yn - xn * (yk_);                         \
    a += act ? term : 0.0f;                                             \
  }
  SHOE(0, s0x, s0y, s1x, s1y) SHOE(1, s1x, s1y, s2x, s2y)
  SHOE(2, s2x, s2y, s3x, s3y) SHOE(3, s3x, s3y, s4x, s4y)
  SHOE(4, s4x, s4y, s5x, s5y) SHOE(5, s5x, s5y, s6x, s6y)
  SHOE(6, s6x, s6y, s7x, s7y) SHOE(7, s7x, s7y, s7x, s7y)
#undef SHOE
  const float inter = 0.5f * fabsf(a);
  const float areaA = 0.5f * fabsf(aA);
  const float areaB = 0.5f * fabsf(sB);
  const float uni = areaA + areaB - inter;
  const float iou = inter / fmaxf(uni, 1e-9f);
  return iou > 0.5f;
}

// ---------------- Kernel 1: per (batch,level) top-K (cheap prescreen, exact keys) --
// Pass 1: cheap f32 sigmoid -> histogram (bucketing only). Pass 2: identical cheap
// recompute; gather approx-bucket >= cutB-1 (rigorous superset: __expf rel err ~2e-5
// << quarter-binade bucket width 12.5%); exact validated f64 sigmoid ONLY on gathered
// (~1.7K worst). Exact 64-bit keys -> selection identical to validated R9.
__global__ __launch_bounds__(1024) void topk_kernel(LevelPtrs P,
    float* __restrict__ candPoly, float* __restrict__ candSc, unsigned* __restrict__ candValid) {
  __shared__ unsigned hist[NSH * HSTR];      // 32832 B
  __shared__ unsigned histT[512];
  __shared__ __align__(16) unsigned long long gbuf[GB];  // 32768 B
  __shared__ int gcount;
  __shared__ int cutB;
  const int blk = blockIdx.x;
  const int b = blk / 5, l = blk % 5;
  const int HW = d_HW[l], K = d_K[l], OFF = d_OFF[l];
  const float* cls = P.cls[l] + (size_t)b * HW;
  const float* reg = P.reg[l] + (size_t)b * 8 * HW;
  const float* loc = P.loc[l];
  const int tid = threadIdx.x;
  const int wave = tid >> 6, lane = tid & 63;

  for (int t = tid; t < NSH * HSTR; t += 1024) hist[t] = 0u;
  if (tid == 0) gcount = 0;
  __syncthreads();

  // pass 1: cheap f32 sigmoid -> histogram of masked-score high bits (bits[31:21])
  const int sh = (tid >> 2) & (NSH - 1);
  for (int idx = tid; idx < HW; idx += 1024) {
    const float x = cls[idx];
    const float sa = 1.0f / (1.0f + __expf(-x));
    const float ma = (sa > 0.05f) ? sa : 0.0f;
    atomicAdd(&hist[sh * HSTR + (__float_as_uint(ma) >> 21)], 1u);
  }
  __syncthreads();
  for (int t = tid; t < 512; t += 1024) {
    unsigned sum = 0;
#pragma unroll
    for (int h = 0; h < NSH; ++h) sum += hist[h * HSTR + t];
    histT[t] = sum;
  }
  __syncthreads();
  // single-wave suffix scan: cutB = largest t with suffix-sum >= K (validated R7)
  if (wave == 0) {
    const int t0 = lane * 8;
    int h[8], loc8[8];
#pragma unroll
    for (int k = 0; k < 8; ++k) h[k] = (int)histT[t0 + k];
    int run = 0;
#pragma unroll
    for (int k = 7; k >= 0; --k) { run += h[k]; loc8[k] = run; }
    int v = run;
#pragma unroll
    for (int d = 1; d < 64; d <<= 1) {
      const int u = __shfl_down(v, d);
      if (lane + d < 64) v += u;
    }
    const int excl = v - run;
    int cand = -1;
#pragma unroll
    for (int k = 7; k >= 0; --k)
      if (cand < 0 && excl + loc8[k] >= K) cand = t0 + k;
    const unsigned long long bal = __ballot(cand >= 0);
    const int hi = 63 - __builtin_clzll(bal);   // nonzero: total == HW >= K
    const int cb = __shfl(cand, hi);
    if (lane == 0) cutB = cb;
  }
  __syncthreads();

  // pass 2: gather approx-bucket >= cutB-1 (superset of exact top-K, slack-1 proof
  // above); EXACT validated sigmoid only for gathered elements.
  const int cb2 = cutB - 1;
  for (int idx = tid; idx < HW; idx += 1024) {
    const float x = cls[idx];
    const float sa = 1.0f / (1.0f + __expf(-x));   // identical recompute of pass 1
    const float ma = (sa > 0.05f) ? sa : 0.0f;
    if ((int)(__float_as_uint(ma) >> 21) >= cb2) {
      // correctly-rounded f32 sigmoid via double (bit-matched XLA R1 — do not change)
      const float s = (float)(1.0 / (1.0 + exp(-(double)x)));
      const float me = (s > 0.05f) ? s : 0.0f;
      const int pos = atomicAdd(&gcount, 1);
      if (pos < GB)
        gbuf[pos] = ((unsigned long long)__float_as_uint(me) << 32)
                  | (unsigned long long)(0xFFFFFFFFu - (unsigned)idx); // tie -> lower idx
    }
  }
  __syncthreads();
  const int G = min(gcount, GB);
  if (tid < 4 && G + tid < GB) gbuf[G + tid] = 0ULL;   // pad so vector loop reads zeros
  __syncthreads();

  // rank-by-count + decode (grid-stride: G can exceed 1024 now)
  const int G4 = (G + 3) & ~3;
  for (int t = tid; t < G; t += 1024) {
    const unsigned long long my = gbuf[t];
    int rank = 0;
    const ulonglong2* g2 = (const ulonglong2*)gbuf;
    for (int j = 0; j < G4 / 2; j += 2) {
      const ulonglong2 a = g2[j], c = g2[j + 1];
      rank += (a.x > my) ? 1 : 0;
      rank += (a.y > my) ? 1 : 0;
      rank += (c.x > my) ? 1 : 0;
      rank += (c.y > my) ? 1 : 0;
    }
    if (rank < K) {
      const float val = __uint_as_float((unsigned)(my >> 32));
      const int idx = (int)(0xFFFFFFFFu - (unsigned)(my & 0xFFFFFFFFULL));
      const float hh = (float)P.img[b * 2 + 0];
      const float ww = (float)P.img[b * 2 + 1];
      const float xmax = ww - 1.0f, ymax = hh - 1.0f;
      const float lx = loc[idx * 2 + 0], ly = loc[idx * 2 + 1];
      const int go = b * T_CAND + OFF + rank;
#pragma unroll
      for (int q = 0; q < 4; ++q) {
        const float rx = reg[(2 * q + 0) * HW + idx];
        const float ry = reg[(2 * q + 1) * HW + idx];
        const float pxv = fminf(fmaxf(lx - rx, 0.0f), xmax);
        const float pyv = fminf(fmaxf(ly - ry, 0.0f), ymax);
        candPoly[go * 8 + 2 * q + 0] = pxv;
        candPoly[go * 8 + 2 * q + 1] = pyv;
      }
      const bool v = (val > 0.05f);   // bw/bh >= MIN_SIZE(0) always true after clip
      candSc[go]    = v ? sqrtf(val) : 0.0f;
      candValid[go] = v ? 1u : 0u;
    }
  }
}

// ---------------- Kernel 2: per-batch stable sort + AABB emit (validated R9) -------
__global__ __launch_bounds__(1024) void sort_kernel(
    const float* __restrict__ candPoly, const float* __restrict__ candSc,
    const unsigned* __restrict__ candValid,
    float* __restrict__ sPoly, float* __restrict__ sSc, unsigned* __restrict__ sValid,
    float* __restrict__ sAABB) {
  __shared__ __align__(16) unsigned long long key[T_CAND];
  const int b = blockIdx.x, tid = threadIdx.x;
  float sc = 0.0f;
  if (tid < T_CAND) {
    sc = candSc[b * T_CAND + tid];
    key[tid] = ((unsigned long long)__float_as_uint(sc) << 32)
             | (unsigned long long)(0xFFFFFFFFu - (unsigned)tid);
  }
  __syncthreads();
  if (tid < T_CAND) {
    const unsigned long long my = key[tid];
    int rank = 0;
    const ulonglong2* k2 = (const ulonglong2*)key;
    for (int j = 0; j < T_CAND / 2; j += 2) {
      const ulonglong2 a = k2[j], c = k2[j + 1];
      rank += (a.x > my) ? 1 : 0;
      rank += (a.y > my) ? 1 : 0;
      rank += (c.x > my) ? 1 : 0;
      rank += (c.y > my) ? 1 : 0;
    }
    sSc[b * T_CAND + rank]    = sc;
    sValid[b * T_CAND + rank] = candValid[b * T_CAND + tid];
    const float4* src = (const float4*)(candPoly + (size_t)(b * T_CAND + tid) * 8);
    const float4 s0 = src[0], s1 = src[1];
    float4* dst = (float4*)(sPoly + (size_t)(b * T_CAND + rank) * 8);
    dst[0] = s0;
    dst[1] = s1;
    float4 bb;  // minx,miny,maxx,maxy
    bb.x = fminf(fminf(s0.x, s0.z), fminf(s1.x, s1.z));
    bb.y = fminf(fminf(s0.y, s0.w), fminf(s1.y, s1.w));
    bb.z = fmaxf(fmaxf(s0.x, s0.z), fmaxf(s1.x, s1.z));
    bb.w = fmaxf(fmaxf(s0.y, s0.w), fmaxf(s1.y, s1.w));
    *(float4*)(sAABB + (size_t)(b * T_CAND + rank) * 4) = bb;
  }
}

// ---------------- Kernel 3: per-tile prescreen + register clip (validated R13) -----
__global__ __launch_bounds__(512) void tileclip_kernel(
    const float* __restrict__ sPoly, const unsigned* __restrict__ sValid,
    const float* __restrict__ sAABB, unsigned long long* __restrict__ MT) {
  __shared__ __align__(16) float4 rBB[64], cBB[64];
  __shared__ __align__(16) float4 rPoly[128], cPolyS[128];
  __shared__ unsigned rV[64], cV[64];
  __shared__ unsigned long long cw[64], ow[64];
  __shared__ unsigned pl[4096];   // 16 KB (64x64 = 4096 max, exactly bounded)
  __shared__ int cnt;
  const int b = blockIdx.y;
  int it = 0, rem = blockIdx.x;
  while (rem >= NW - it) { rem -= NW - it; ++it; }
  const int jt = it + rem;
  const int tid = threadIdx.x;
  const int wave = tid >> 6, lane = tid & 63;

  if (tid == 0) cnt = 0;
  if (tid < 64) {
    const int row = it * 64 + tid;
    const int rc = row < T_CAND ? row : (T_CAND - 1);
    rBB[tid] = *(const float4*)(sAABB + (size_t)(b * T_CAND + rc) * 4);
    rV[tid]  = (row < T_CAND) ? sValid[b * T_CAND + row] : 0u;
    ow[tid]  = 0ULL;
  } else if (tid < 128) {
    const int t2 = tid - 64;
    const int col = jt * 64 + t2;
    const int cc = col < T_CAND ? col : (T_CAND - 1);
    cBB[t2] = *(const float4*)(sAABB + (size_t)(b * T_CAND + cc) * 4);
    cV[t2]  = (col < T_CAND) ? sValid[b * T_CAND + col] : 0u;
  } else if (tid < 256) {
    const int t2 = tid - 128;                 // rPoly[t2]
    const int row = it * 64 + (t2 >> 1);
    const int rc = row < T_CAND ? row : (T_CAND - 1);
    rPoly[t2] = ((const float4*)(sPoly + (size_t)(b * T_CAND + rc) * 8))[t2 & 1];
  } else if (tid < 384) {
    const int t2 = tid - 256;                 // cPolyS[t2]
    const int col = jt * 64 + (t2 >> 1);
    const int cc = col < T_CAND ? col : (T_CAND - 1);
    cPolyS[t2] = ((const float4*)(sPoly + (size_t)(b * T_CAND + cc) * 8))[t2 & 1];
  }
  __syncthreads();

  // prescreen: 8 waves x 8 rows; lane = column offset (predicate validated R8)
  const float4 jbb = cBB[lane];
  const bool jv = (cV[lane] != 0u) && (jt * 64 + lane < T_CAND);
  const int j = jt * 64 + lane;
#pragma unroll
  for (int k = 0; k < 8; ++k) {
    const int r = wave * 8 + k;
    const int irow = it * 64 + r;
    const float4 ib = rBB[r];
    const bool iv = rV[r] != 0u;
    const bool ov = !(ib.z < jbb.x || jbb.z < ib.x || ib.w < jbb.y || jbb.w < ib.y);
    const bool pred = iv && jv && (j > irow) && ov;
    const unsigned long long w = __ballot(pred);
    if (lane == 0) cw[r] = w;
  }
  __syncthreads();
  if (tid < 64) {
    unsigned long long w = cw[tid];
    const int c = __popcll(w);
    int off = c ? atomicAdd(&cnt, c) : 0;
    while (w) {
      const int jo = (int)__builtin_ctzll(w);
      w &= w - 1;
      pl[off++] = ((unsigned)tid << 6) | (unsigned)jo;
    }
  }
  __syncthreads();
  const int total = cnt;
  for (int p = tid; p < total; p += 512) {
    const unsigned pk = pl[p];
    const int io = (int)(pk >> 6), jo = (int)(pk & 63u);
    if (clip_hit4(rPoly[2 * io], rPoly[2 * io + 1], cPolyS[2 * jo], cPolyS[2 * jo + 1]))
      atomicOr(&ow[io], 1ULL << jo);
  }
  __syncthreads();
  if (tid < 64) {
    const int row = it * 64 + tid;
    if (row < T_CAND) MT[((size_t)b * NW + jt) * T_CAND + row] = ow[tid];
  }
}

// ---------------- Kernel 4: greedy NMS resolve (scalarized, validated R9) + emit ---
__global__ __launch_bounds__(1024) void nms_resolve_emit_kernel(
    const unsigned long long* __restrict__ MT, const unsigned* __restrict__ sValid,
    const float* __restrict__ sPoly, const float* __restrict__ sSc, float* __restrict__ out) {
  __shared__ __align__(16) unsigned long long mt[NW * T_CAND];  // 95,872 B
  __shared__ unsigned long long vb[16];
  __shared__ unsigned long long kw[NW];
  const int b = blockIdx.x;
  const int tid = threadIdx.x;
  const int wave = tid >> 6, lane = tid & 63;

  {
    const ulonglong2* g2 = (const ulonglong2*)(MT + (size_t)b * NW * T_CAND);
    ulonglong2* l2 = (ulonglong2*)mt;
    for (int t = tid; t < NW * T_CAND / 2; t += 1024) l2[t] = g2[t];
  }
  if (wave < NW) {
    const int idx = wave * 64 + lane;
    const bool v = (idx < T_CAND) && (sValid[b * T_CAND + idx] != 0u);
    const unsigned long long ball = __ballot(v);
    if (lane == 0) vb[wave] = ball;
  }
  __syncthreads();

  if (wave == 0) {
    unsigned long long kwreg = 0ULL;   // lane q holds keep-word of resolved block q
    for (int q = 0; q < NW; ++q) {
      const unsigned long long* col = &mt[q * T_CAND];
      const int nrow = q * 64 + lane;
      const unsigned long long sup = col[nrow < T_CAND ? nrow : (T_CAND - 1)];
      unsigned long long acc = 0ULL;
      for (int wp = 0; wp < q; ++wp) {
        const unsigned long long row = col[wp * 64 + lane];
        const unsigned long long kword = readlane64(kwreg, wp);
        acc |= ((kword >> lane) & 1ULL) ? row : 0ULL;
      }
#pragma unroll
      for (int m = 1; m < 64; m <<= 1)
        acc |= (unsigned long long)__shfl_xor((long long)acc, m, 64);
      const unsigned long long S = rfl64(acc);
      const unsigned long long validq = rfl64(vb[q]);
      unsigned long long alive = validq & ~S;
      const unsigned long long suppr = __ballot(sup != 0ULL);
      unsigned long long rm = alive & suppr;
      while (rm) {
        const int s = (int)__builtin_ctzll(rm);
        rm &= rm - 1;
        if ((alive >> s) & 1ULL) {
          alive &= ~readlane64(sup, s);
          rm &= alive;
        }
      }
      if (lane == q) kwreg = alive;
    }
    if (lane < NW) kw[lane] = kwreg;
  }
  __syncthreads();

  if (tid < 100) {
    const int o = tid;
    int totalKeep = 0;
    for (int w = 0; w < NW; ++w) totalKeep += __popcll(kw[w]);
    const bool kept = o < totalKeep;
    int idx = 0;
    if (kept) {
      int r = o, w = 0;
      unsigned long long word = 0ULL;
      for (; w < NW; ++w) {
        word = kw[w];
        const int c = __popcll(word);
        if (r < c) break;
        r -= c;
      }
      for (int p = 0; p < r; ++p) word &= word - 1;
      idx = w * 64 + (__ffsll(word) - 1);
    } else {
      int r = o - totalKeep, w = 0;
      unsigned long long word = 0ULL;
      for (; w < NW; ++w) {
        const unsigned long long mk = (w == NW - 1)
            ? ((1ULL << (T_CAND - 64 * (NW - 1))) - 1ULL) : ~0ULL;
        word = (~kw[w]) & mk;
        const int c = __popcll(word);
        if (r < c) break;
        r -= c;
      }
      for (int p = 0; p < r; ++p) word &= word - 1;
      idx = w * 64 + (__ffsll(word) - 1);
    }
    const float4* pp = (const float4*)(sPoly + (size_t)(b * T_CAND + idx) * 8);
    float4* ob2 = (float4*)(out + (size_t)b * 800 + (size_t)o * 8);
    ob2[0] = pp[0];
    ob2[1] = pp[1];
    out[1600 + b * 100 + o] = kept ? sSc[b * T_CAND + idx] : 0.0f;  // where(ok, top_s, 0)
    out[1800 + b * 100 + o] = 1.0f;                                 // labels always 1 (C=1)
    out[2000 + b * 100 + o] = kept ? 1.0f : 0.0f;                   // ok
  }
}

extern "C" void kernel_launch(void* const* d_in, const int* in_sizes, int n_in,
                              void* d_out, int out_size, void* d_ws, size_t ws_size,
                              hipStream_t stream) {
  (void)n_in; (void)out_size; (void)ws_size;
  LevelPtrs P;
  const bool interleaved = (in_sizes[2] == 204800);
  for (int l = 0; l < 5; ++l) {
    if (interleaved) {
      P.loc[l] = (const float*)d_in[4 * l + 0];
      P.cls[l] = (const float*)d_in[4 * l + 1];
      P.reg[l] = (const float*)d_in[4 * l + 2];
    } else {
      P.loc[l] = (const float*)d_in[l];
      P.cls[l] = (const float*)d_in[5 + l];
      P.reg[l] = (const float*)d_in[10 + l];
    }
  }
  P.img = (const int*)d_in[20];

  char* ws = (char*)d_ws;
  float*    candPoly  = (float*)(ws + 0);          // 54784 (16B aligned)
  float*    candSc    = (float*)(ws + 54784);      // 6848
  unsigned* candValid = (unsigned*)(ws + 61632);   // 6848
  float*    sPoly     = (float*)(ws + 68480);      // 54784 (16B aligned)
  float*    sSc       = (float*)(ws + 123264);     // 6848
  unsigned* sValid    = (unsigned*)(ws + 130112);  // 6848
  float*    sAABB     = (float*)(ws + 136960);     // 27392 (16B aligned)
  unsigned long long* MT = (unsigned long long*)(ws + 164352); // 191744

  topk_kernel<<<dim3(10), dim3(1024), 0, stream>>>(P, candPoly, candSc, candValid);
  sort_kernel<<<dim3(2), dim3(1024), 0, stream>>>(candPoly, candSc, candValid,
                                                  sPoly, sSc, sValid, sAABB);
  tileclip_kernel<<<dim3(105, 2), dim3(512), 0, stream>>>(sPoly, sValid, sAABB, MT);
  nms_resolve_emit_kernel<<<dim3(2), dim3(1024), 0, stream>>>(MT, sValid, sPoly, sSc,
                                                              (float*)d_out);
}

// Round 16
// 75.960 us; speedup vs baseline: 1.7608x; 1.7608x over previous
//
#include <hip/hip_runtime.h>

#pragma clang fp contract(off)

#define T_CAND 856
#define NW 14          // ceil(856/64)
#define NSH 16         // sub-histograms (split by (tid>>2)&15 to cut same-address atomics)
#define HSTR 1025      // sub-hist stride in words (odd -> banks spread); 1024 buckets
#define GB 2048        // gather buffer entries (expected G <= ~400/level)

__device__ const int d_HW[5]  = {12800, 3200, 800, 208, 56};
__device__ const int d_K[5]   = {200, 200, 200, 200, 56};
__device__ const int d_OFF[5] = {0, 200, 400, 600, 800};

struct LevelPtrs {
  const float* loc[5];
  const float* cls[5];
  const float* reg[5];
  const int*   img;
};

__device__ __forceinline__ unsigned long long readlane64(unsigned long long v, int lane) {
  const unsigned lo = (unsigned)__builtin_amdgcn_readlane((int)(unsigned)(v & 0xFFFFFFFFULL), lane);
  const unsigned hi = (unsigned)__builtin_amdgcn_readlane((int)(unsigned)(v >> 32), lane);
  return ((unsigned long long)hi << 32) | lo;
}
__device__ __forceinline__ unsigned long long rfl64(unsigned long long v) {
  const unsigned lo = (unsigned)__builtin_amdgcn_readfirstlane((int)(unsigned)(v & 0xFFFFFFFFULL));
  const unsigned hi = (unsigned)__builtin_amdgcn_readfirstlane((int)(unsigned)(v >> 32));
  return ((unsigned long long)hi << 32) | lo;
}

// order-isomorphic bit transform: x1 < x2 (floats, no NaN) <=> ord(x1) < ord(x2) (uints)
__device__ __forceinline__ unsigned ordbits(float x) {
  const unsigned u = __float_as_uint(x);
  return (u & 0x80000000u) ? ~u : (u | 0x80000000u);
}

// ---------------- Kernel 1: per (batch,level) top-K via x-key radix select ---------
// Sigmoid is monotone in x => top-K by masked score == top-K by x among unmasked,
// with zeros (s<=0.05 <=> x <= -2.944) ranked below by index. Pass 1 histograms the
// EXACT x order-key (no exp at all). Pass 2 gathers bucket >= cutB (exact superset of
// top-K, same suffix argument as validated R2+) plus ALL potentially-masked elements
// (x < -2.9f) so zero-ordering is globally exact; the validated f64 sigmoid runs only
// on gathered (~350/level). Exact 64-bit keys -> selection identical to validated R1.
__global__ __launch_bounds__(1024) void topk_kernel(LevelPtrs P,
    float* __restrict__ candPoly, float* __restrict__ candSc, unsigned* __restrict__ candValid,
    unsigned* __restrict__ pairCount) {
  __shared__ unsigned hist[NSH * HSTR];      // 65600 B
  __shared__ unsigned histT[1024];           // 4096 B
  __shared__ __align__(16) unsigned long long gbuf[GB];  // 16384 B
  __shared__ int gcount;
  __shared__ int cutB;
  const int blk = blockIdx.x;
  const int b = blk / 5, l = blk % 5;
  const int HW = d_HW[l], K = d_K[l], OFF = d_OFF[l];
  const float* cls = P.cls[l] + (size_t)b * HW;
  const float* reg = P.reg[l] + (size_t)b * 8 * HW;
  const float* loc = P.loc[l];
  const int tid = threadIdx.x;
  const int wave = tid >> 6, lane = tid & 63;

  if (blk == 0 && tid == 0) *pairCount = 0u;   // consumed 2 kernels later (boundary-ordered)
  for (int t = tid; t < NSH * HSTR; t += 1024) hist[t] = 0u;
  if (tid == 0) gcount = 0;
  __syncthreads();

  // pass 1: histogram of x order-key top bits (1024 half-binade buckets; no exp)
  const int sh = (tid >> 2) & (NSH - 1);
  for (int idx = tid; idx < HW; idx += 1024) {
    const unsigned bkt = ordbits(cls[idx]) >> 22;
    atomicAdd(&hist[sh * HSTR + bkt], 1u);
  }
  __syncthreads();
  for (int t = tid; t < 1024; t += 1024) {
    unsigned sum = 0;
#pragma unroll
    for (int h = 0; h < NSH; ++h) sum += hist[h * HSTR + t];
    histT[t] = sum;
  }
  __syncthreads();
  // single-wave suffix scan over 1024 buckets (16/lane): cutB = largest t with
  // suffix-sum >= K (same scheme as validated R7 scan, widened 8->16)
  if (wave == 0) {
    const int t0 = lane * 16;
    int h[16], loc16[16];
#pragma unroll
    for (int k = 0; k < 16; ++k) h[k] = (int)histT[t0 + k];
    int run = 0;
#pragma unroll
    for (int k = 15; k >= 0; --k) { run += h[k]; loc16[k] = run; }
    int v = run;
#pragma unroll
    for (int d = 1; d < 64; d <<= 1) {
      const int u = __shfl_down(v, d);
      if (lane + d < 64) v += u;
    }
    const int excl = v - run;   // sum of totals of lanes > lane
    int cand = -1;
#pragma unroll
    for (int k = 15; k >= 0; --k)
      if (cand < 0 && excl + loc16[k] >= K) cand = t0 + k;
    const unsigned long long bal = __ballot(cand >= 0);
    const int hi = 63 - __builtin_clzll(bal);   // nonzero: total == HW >= K
    const int cb = __shfl(cand, hi);
    if (lane == 0) cutB = cb;
  }
  __syncthreads();

  // pass 2: gather exact-key bucket >= cutB (superset of top-K) OR potentially-masked
  // (x < -2.9f superset of {s <= 0.05f}); exact validated sigmoid only on gathered.
  const int cb = cutB;
  for (int idx = tid; idx < HW; idx += 1024) {
    const float x = cls[idx];
    if ((int)(ordbits(x) >> 22) >= cb || x < -2.9f) {
      // correctly-rounded f32 sigmoid via double (bit-matched XLA R1 — do not change)
      const float s = (float)(1.0 / (1.0 + exp(-(double)x)));
      const float m = (s > 0.05f) ? s : 0.0f;
      const int pos = atomicAdd(&gcount, 1);
      if (pos < GB)
        gbuf[pos] = ((unsigned long long)__float_as_uint(m) << 32)
                  | (unsigned long long)(0xFFFFFFFFu - (unsigned)idx); // tie -> lower idx
    }
  }
  __syncthreads();
  const int G = min(gcount, GB);
  if (tid < 4 && G + tid < GB) gbuf[G + tid] = 0ULL;   // pad so vector loop reads zeros
  __syncthreads();

  // rank-by-count + decode (grid-stride; exact keys => identical to validated select)
  const int G4 = (G + 3) & ~3;
  for (int t = tid; t < G; t += 1024) {
    const unsigned long long my = gbuf[t];
    int rank = 0;
    const ulonglong2* g2 = (const ulonglong2*)gbuf;
    for (int j = 0; j < G4 / 2; j += 2) {
      const ulonglong2 a = g2[j], c = g2[j + 1];
      rank += (a.x > my) ? 1 : 0;
      rank += (a.y > my) ? 1 : 0;
      rank += (c.x > my) ? 1 : 0;
      rank += (c.y > my) ? 1 : 0;
    }
    if (rank < K) {
      const float val = __uint_as_float((unsigned)(my >> 32));
      const int idx = (int)(0xFFFFFFFFu - (unsigned)(my & 0xFFFFFFFFULL));
      const float hh = (float)P.img[b * 2 + 0];
      const float ww = (float)P.img[b * 2 + 1];
      const float xmax = ww - 1.0f, ymax = hh - 1.0f;
      const float lx = loc[idx * 2 + 0], ly = loc[idx * 2 + 1];
      const int go = b * T_CAND + OFF + rank;
#pragma unroll
      for (int q = 0; q < 4; ++q) {
        const float rx = reg[(2 * q + 0) * HW + idx];
        const float ry = reg[(2 * q + 1) * HW + idx];
        const float pxv = fminf(fmaxf(lx - rx, 0.0f), xmax);
        const float pyv = fminf(fmaxf(ly - ry, 0.0f), ymax);
        candPoly[go * 8 + 2 * q + 0] = pxv;
        candPoly[go * 8 + 2 * q + 1] = pyv;
      }
      const bool v = (val > 0.05f);   // bw/bh >= MIN_SIZE(0) always true after clip
      candSc[go]    = v ? sqrtf(val) : 0.0f;
      candValid[go] = v ? 1u : 0u;
    }
  }
}

// ---------------- Kernel 2: per-batch stable sort + AABB emit (validated R9) -------
__global__ __launch_bounds__(1024) void sort_kernel(
    const float* __restrict__ candPoly, const float* __restrict__ candSc,
    const unsigned* __restrict__ candValid,
    float* __restrict__ sPoly, float* __restrict__ sSc, unsigned* __restrict__ sValid,
    float* __restrict__ sAABB) {
  __shared__ __align__(16) unsigned long long key[T_CAND];
  const int b = blockIdx.x, tid = threadIdx.x;
  float sc = 0.0f;
  if (tid < T_CAND) {
    sc = candSc[b * T_CAND + tid];
    key[tid] = ((unsigned long long)__float_as_uint(sc) << 32)
             | (unsigned long long)(0xFFFFFFFFu - (unsigned)tid);
  }
  __syncthreads();
  if (tid < T_CAND) {
    const unsigned long long my = key[tid];
    int rank = 0;
    const ulonglong2* k2 = (const ulonglong2*)key;
    for (int j = 0; j < T_CAND / 2; j += 2) {
      const ulonglong2 a = k2[j], c = k2[j + 1];
      rank += (a.x > my) ? 1 : 0;
      rank += (a.y > my) ? 1 : 0;
      rank += (c.x > my) ? 1 : 0;
      rank += (c.y > my) ? 1 : 0;
    }
    sSc[b * T_CAND + rank]    = sc;
    sValid[b * T_CAND + rank] = candValid[b * T_CAND + tid];
    const float4* src = (const float4*)(candPoly + (size_t)(b * T_CAND + tid) * 8);
    const float4 s0 = src[0], s1 = src[1];
    float4* dst = (float4*)(sPoly + (size_t)(b * T_CAND + rank) * 8);
    dst[0] = s0;
    dst[1] = s1;
    float4 bb;  // minx,miny,maxx,maxy
    bb.x = fminf(fminf(s0.x, s0.z), fminf(s1.x, s1.z));
    bb.y = fminf(fminf(s0.y, s0.w), fminf(s1.y, s1.w));
    bb.z = fmaxf(fmaxf(s0.x, s0.z), fmaxf(s1.x, s1.z));
    bb.w = fmaxf(fmaxf(s0.y, s0.w), fmaxf(s1.y, s1.w));
    *(float4*)(sAABB + (size_t)(b * T_CAND + rank) * 4) = bb;
  }
}

// ---------------- Kernel 3: AABB prescreen per tile -> global pair list + MT zero --
// (validated R9) Grid (105 triangular tiles, 2 batches) x 256. One global atomicAdd
// per tile. Tile (it,jt) zero-stores its owned MT words; clip atomicOrs on top.
__global__ __launch_bounds__(256) void pairs_kernel(
    const unsigned* __restrict__ sValid, const float* __restrict__ sAABB,
    unsigned long long* __restrict__ MT, unsigned* __restrict__ pairList,
    unsigned* __restrict__ pairCount) {
  __shared__ __align__(16) float4 ra[64];
  __shared__ unsigned rv[64];
  __shared__ unsigned long long cw[64];
  __shared__ int rowoff[64];
  __shared__ int lcnt;
  __shared__ int gbase;
  const int b = blockIdx.y;
  int it = 0, rem = blockIdx.x;
  while (rem >= NW - it) { rem -= NW - it; ++it; }
  const int jt = it + rem;
  const int tid = threadIdx.x;
  const int wave = tid >> 6, lane = tid & 63;

  if (tid == 0) lcnt = 0;
  if (tid < 64) {
    const int row = it * 64 + tid;
    const int rc = row < T_CAND ? row : (T_CAND - 1);
    ra[tid] = *(const float4*)(sAABB + (size_t)(b * T_CAND + rc) * 4);
    rv[tid] = (row < T_CAND) ? sValid[b * T_CAND + row] : 0u;
    if (row < T_CAND) MT[((size_t)b * NW + jt) * T_CAND + row] = 0ULL;
  }
  __syncthreads();

  // prescreen: 4 waves x 16 rows; lane = column offset (predicate validated R8)
  const int j = jt * 64 + lane;
  const int jcl = j < T_CAND ? j : (T_CAND - 1);
  const float4 jb = *(const float4*)(sAABB + (size_t)(b * T_CAND + jcl) * 4);
  const bool jv = (j < T_CAND) && (sValid[b * T_CAND + jcl] != 0u);
#pragma unroll
  for (int k = 0; k < 16; ++k) {
    const int r = wave * 16 + k;
    const int irow = it * 64 + r;
    const float4 ib = ra[r];                       // uniform LDS broadcast
    const bool iv = rv[r] != 0u;
    const bool ov = !(ib.z < jb.x || jb.z < ib.x || ib.w < jb.y || jb.w < ib.y);
    const bool pred = iv && jv && (j > irow) && ov;
    const unsigned long long w = __ballot(pred);
    if (lane == 0) cw[r] = w;
  }
  __syncthreads();
  if (tid < 64) {
    const int c = __popcll(cw[tid]);
    rowoff[tid] = c ? atomicAdd(&lcnt, c) : 0;
  }
  __syncthreads();
  if (tid == 0) gbase = lcnt ? (int)atomicAdd(pairCount, (unsigned)lcnt) : 0;
  __syncthreads();
  if (tid < 64) {
    unsigned long long w = cw[tid];
    unsigned off = (unsigned)(gbase + rowoff[tid]);
    const int iRow = it * 64 + tid;
    while (w) {
      const int jo = (int)__builtin_ctzll(w);
      w &= w - 1;
      pairList[off++] = ((unsigned)b << 20) | ((unsigned)iRow << 10) | (unsigned)(jt * 64 + jo);
    }
  }
}

// ---------------- Kernel 4: register-only polygon-clip IoU (validated R9) ----------
__global__ __launch_bounds__(256) void clip_kernel(
    const unsigned* __restrict__ pairList, const unsigned* __restrict__ pairCount,
    const float* __restrict__ sPoly, unsigned long long* __restrict__ MT) {
  const int tid = threadIdx.x;
  const unsigned count = *pairCount;
  for (unsigned t0 = blockIdx.x * 256 + tid; t0 < count; t0 += gridDim.x * 256) {
    const unsigned pk = pairList[t0];
    const int b = (pk >> 20) & 1, i = (pk >> 10) & 1023, j = pk & 1023;
    const float4* Ap4 = (const float4*)(sPoly + (size_t)(b * T_CAND + i) * 8);
    const float4 a01 = Ap4[0], a23 = Ap4[1];
    const float ax0 = a01.x, ay0 = a01.y, ax1 = a01.z, ay1 = a01.w,
                ax2 = a23.x, ay2 = a23.y, ax3 = a23.z, ay3 = a23.w;
    const float4* Bp4 = (const float4*)(sPoly + (size_t)(b * T_CAND + j) * 8);
    const float4 b01 = Bp4[0], b23 = Bp4[1];
    const float bx0 = b01.x, by0 = b01.y, bx1 = b01.z, by1 = b01.w,
                bx2 = b23.x, by2 = b23.y, bx3 = b23.z, by3 = b23.w;
    float sB = bx0 * by1 - bx1 * by0;
    sB += bx1 * by2 - bx2 * by1;
    sB += bx2 * by3 - bx3 * by2;
    sB += bx3 * by0 - bx0 * by3;
    const float orient = (sB >= 0.0f) ? 1.0f : -1.0f;
    float aA = ax0 * ay1 - ax1 * ay0;
    aA += ax1 * ay2 - ax2 * ay1;
    aA += ax2 * ay3 - ax3 * ay2;
    aA += ax3 * ay0 - ax0 * ay3;

    float s0x = ax0, s0y = ay0, s1x = ax1, s1y = ay1,
          s2x = ax2, s2y = ay2, s3x = ax3, s3y = ay3,
          s4x = 0.f, s4y = 0.f, s5x = 0.f, s5y = 0.f,
          s6x = 0.f, s6y = 0.f, s7x = 0.f, s7y = 0.f;
    int n = 4;
    float lastx = ax3, lasty = ay3;          // V[n-1] of initial polygon
    const float bex[5] = {bx0, bx1, bx2, bx3, bx0};
    const float bey[5] = {by0, by1, by2, by3, by0};

#define PUSH(w_, vx_, vy_)                                              \
    {                                                                   \
      const bool w__ = (w_);                                            \
      const float vx__ = (vx_), vy__ = (vy_);                           \
      t0x = (w__ && cnt == 0) ? vx__ : t0x; t0y = (w__ && cnt == 0) ? vy__ : t0y; \
      t1x = (w__ && cnt == 1) ? vx__ : t1x; t1y = (w__ && cnt == 1) ? vy__ : t1y; \
      t2x = (w__ && cnt == 2) ? vx__ : t2x; t2y = (w__ && cnt == 2) ? vy__ : t2y; \
      t3x = (w__ && cnt == 3) ? vx__ : t3x; t3y = (w__ && cnt == 3) ? vy__ : t3y; \
      t4x = (w__ && cnt == 4) ? vx__ : t4x; t4y = (w__ && cnt == 4) ? vy__ : t4y; \
      t5x = (w__ && cnt == 5) ? vx__ : t5x; t5y = (w__ && cnt == 5) ? vy__ : t5y; \
      t6x = (w__ && cnt == 6) ? vx__ : t6x; t6y = (w__ && cnt == 6) ? vy__ : t6y; \
      t7x = (w__ && cnt == 7) ? vx__ : t7x; t7y = (w__ && cnt == 7) ? vy__ : t7y; \
      nlx = (w__ && cnt < 8) ? vx__ : nlx;  nly = (w__ && cnt < 8) ? vy__ : nly;  \
      cnt += w__ ? 1 : 0;                                               \
    }

#define CLIP_K(k_, sx_, sy_)                                            \
    {                                                                   \
      const bool act = (k_) < n;                                        \
      const float cx = sx_, cy = sy_;                                   \
      const float sc2 = orient * (dx * (cy - p1y) - dy * (cx - p1x));   \
      const bool cin = (sc2 >= 0.0f), pin = (sp >= 0.0f);               \
      const float den = sp - sc2;                                       \
      const float dd = (fabsf(den) > 1e-9f) ? den : 1e-9f;              \
      const float tt = sp / dd;                                         \
      const float ipx = px + tt * (cx - px);                            \
      const float ipy = py + tt * (cy - py);                            \
      PUSH(act && (cin != pin), ipx, ipy);                              \
      PUSH(act && cin, cx, cy);                                         \
      px = cx; py = cy; sp = sc2;                                       \
    }

#pragma unroll
    for (int e = 0; e < 4; ++e) {
      const float p1x = bex[e], p1y = bey[e];
      const float dx = bex[e + 1] - p1x, dy = bey[e + 1] - p1y;
      float t0x = 0.f, t0y = 0.f, t1x = 0.f, t1y = 0.f, t2x = 0.f, t2y = 0.f,
            t3x = 0.f, t3y = 0.f, t4x = 0.f, t4y = 0.f, t5x = 0.f, t5y = 0.f,
            t6x = 0.f, t6y = 0.f, t7x = 0.f, t7y = 0.f;
      float nlx = lastx, nly = lasty;
      int cnt = 0;
      float px = lastx, py = lasty;
      float sp = orient * (dx * (py - p1y) - dy * (px - p1x));
      CLIP_K(0, s0x, s0y) CLIP_K(1, s1x, s1y) CLIP_K(2, s2x, s2y) CLIP_K(3, s3x, s3y)
      CLIP_K(4, s4x, s4y) CLIP_K(5, s5x, s5y) CLIP_K(6, s6x, s6y) CLIP_K(7, s7x, s7y)
      s0x = t0x; s0y = t0y; s1x = t1x; s1y = t1y; s2x = t2x; s2y = t2y;
      s3x = t3x; s3y = t3y; s4x = t4x; s4y = t4y; s5x = t5x; s5y = t5y;
      s6x = t6x; s6y = t6y; s7x = t7x; s7y = t7y;
      lastx = nlx; lasty = nly;
      n = cnt;           // raw (may exceed 8) — matches validated semantics
    }
#undef CLIP_K
#undef PUSH

    float a = 0.0f;
#define SHOE(k_, xk_, yk_, xn_, yn_)                                    \
    {                                                                   \
      const bool act = (k_) < n;                                        \
      const bool wrap = (k_) == n - 1;                                  \
      const float xn = wrap ? s0x : (xn_);                              \
      const float yn = wrap ? s0y : (yn_);                              \
      const float term = (xk_) * yn - xn * (yk_);                       \
      a += act ? term : 0.0f;                                           \
    }
    SHOE(0, s0x, s0y, s1x, s1y) SHOE(1, s1x, s1y, s2x, s2y)
    SHOE(2, s2x, s2y, s3x, s3y) SHOE(3, s3x, s3y, s4x, s4y)
    SHOE(4, s4x, s4y, s5x, s5y) SHOE(5, s5x, s5y, s6x, s6y)
    SHOE(6, s6x, s6y, s7x, s7y) SHOE(7, s7x, s7y, s7x, s7y)
#undef SHOE
    const float inter = 0.5f * fabsf(a);
    const float areaA = 0.5f * fabsf(aA);
    const float areaB = 0.5f * fabsf(sB);
    const float uni = areaA + areaB - inter;
    const float iou = inter / fmaxf(uni, 1e-9f);
    if (iou > 0.5f)
      atomicOr(&MT[((size_t)b * NW + (j >> 6)) * T_CAND + i], 1ULL << (j & 63));
  }
}

// ---------------- Kernel 5: greedy NMS resolve (scalarized, validated R9) + emit ---
__global__ __launch_bounds__(1024) void nms_resolve_emit_kernel(
    const unsigned long long* __restrict__ MT, const unsigned* __restrict__ sValid,
    const float* __restrict__ sPoly, const float* __restrict__ sSc, float* __restrict__ out) {
  __shared__ __align__(16) unsigned long long mt[NW * T_CAND];  // 95,872 B
  __shared__ unsigned long long vb[16];
  __shared__ unsigned long long kw[NW];
  const int b = blockIdx.x;
  const int tid = threadIdx.x;
  const int wave = tid >> 6, lane = tid & 63;

  {
    const ulonglong2* g2 = (const ulonglong2*)(MT + (size_t)b * NW * T_CAND);
    ulonglong2* l2 = (ulonglong2*)mt;
    for (int t = tid; t < NW * T_CAND / 2; t += 1024) l2[t] = g2[t];
  }
  if (wave < NW) {
    const int idx = wave * 64 + lane;
    const bool v = (idx < T_CAND) && (sValid[b * T_CAND + idx] != 0u);
    const unsigned long long ball = __ballot(v);
    if (lane == 0) vb[wave] = ball;
  }
  __syncthreads();

  if (wave == 0) {
    unsigned long long kwreg = 0ULL;   // lane q holds keep-word of resolved block q
    for (int q = 0; q < NW; ++q) {
      const unsigned long long* col = &mt[q * T_CAND];
      const int nrow = q * 64 + lane;
      const unsigned long long sup = col[nrow < T_CAND ? nrow : (T_CAND - 1)];
      unsigned long long acc = 0ULL;
      for (int wp = 0; wp < q; ++wp) {
        const unsigned long long row = col[wp * 64 + lane];
        const unsigned long long kword = readlane64(kwreg, wp);
        acc |= ((kword >> lane) & 1ULL) ? row : 0ULL;
      }
#pragma unroll
      for (int m = 1; m < 64; m <<= 1)
        acc |= (unsigned long long)__shfl_xor((long long)acc, m, 64);
      const unsigned long long S = rfl64(acc);
      const unsigned long long validq = rfl64(vb[q]);
      unsigned long long alive = validq & ~S;
      const unsigned long long suppr = __ballot(sup != 0ULL);
      unsigned long long rm = alive & suppr;
      while (rm) {
        const int s = (int)__builtin_ctzll(rm);
        rm &= rm - 1;
        if ((alive >> s) & 1ULL) {
          alive &= ~readlane64(sup, s);
          rm &= alive;
        }
      }
      if (lane == q) kwreg = alive;
    }
    if (lane < NW) kw[lane] = kwreg;
  }
  __syncthreads();

  if (tid < 100) {
    const int o = tid;
    int totalKeep = 0;
    for (int w = 0; w < NW; ++w) totalKeep += __popcll(kw[w]);
    const bool kept = o < totalKeep;
    int idx = 0;
    if (kept) {
      int r = o, w = 0;
      unsigned long long word = 0ULL;
      for (; w < NW; ++w) {
        word = kw[w];
        const int c = __popcll(word);
        if (r < c) break;
        r -= c;
      }
      for (int p = 0; p < r; ++p) word &= word - 1;
      idx = w * 64 + (__ffsll(word) - 1);
    } else {
      int r = o - totalKeep, w = 0;
      unsigned long long word = 0ULL;
      for (; w < NW; ++w) {
        const unsigned long long mk = (w == NW - 1)
            ? ((1ULL << (T_CAND - 64 * (NW - 1))) - 1ULL) : ~0ULL;
        word = (~kw[w]) & mk;
        const int c = __popcll(word);
        if (r < c) break;
        r -= c;
      }
      for (int p = 0; p < r; ++p) word &= word - 1;
      idx = w * 64 + (__ffsll(word) - 1);
    }
    const float4* pp = (const float4*)(sPoly + (size_t)(b * T_CAND + idx) * 8);
    float4* ob2 = (float4*)(out + (size_t)b * 800 + (size_t)o * 8);
    ob2[0] = pp[0];
    ob2[1] = pp[1];
    out[1600 + b * 100 + o] = kept ? sSc[b * T_CAND + idx] : 0.0f;  // where(ok, top_s, 0)
    out[1800 + b * 100 + o] = 1.0f;                                 // labels always 1 (C=1)
    out[2000 + b * 100 + o] = kept ? 1.0f : 0.0f;                   // ok
  }
}

extern "C" void kernel_launch(void* const* d_in, const int* in_sizes, int n_in,
                              void* d_out, int out_size, void* d_ws, size_t ws_size,
                              hipStream_t stream) {
  (void)n_in; (void)out_size; (void)ws_size;
  LevelPtrs P;
  const bool interleaved = (in_sizes[2] == 204800);
  for (int l = 0; l < 5; ++l) {
    if (interleaved) {
      P.loc[l] = (const float*)d_in[4 * l + 0];
      P.cls[l] = (const float*)d_in[4 * l + 1];
      P.reg[l] = (const float*)d_in[4 * l + 2];
    } else {
      P.loc[l] = (const float*)d_in[l];
      P.cls[l] = (const float*)d_in[5 + l];
      P.reg[l] = (const float*)d_in[10 + l];
    }
  }
  P.img = (const int*)d_in[20];

  char* ws = (char*)d_ws;
  float*    candPoly  = (float*)(ws + 0);          // 54784
  float*    candSc    = (float*)(ws + 54784);      // 6848
  unsigned* candValid = (unsigned*)(ws + 61632);   // 6848
  float*    sPoly     = (float*)(ws + 68480);      // 54784 (16B aligned)
  float*    sSc       = (float*)(ws + 123264);     // 6848
  unsigned* sValid    = (unsigned*)(ws + 130112);  // 6848
  unsigned long long* MT = (unsigned long long*)(ws + 136960); // 191744 -> 328704
  float*    sAABB     = (float*)(ws + 328704);     // 27392 -> 356096
  unsigned* pairCount = (unsigned*)(ws + 356096);  // 4 (pad to 356112)
  unsigned* pairList  = (unsigned*)(ws + 356112);  // max 856*855/2*2*4 = 2,927,520 B

  topk_kernel<<<dim3(10), dim3(1024), 0, stream>>>(P, candPoly, candSc, candValid, pairCount);
  sort_kernel<<<dim3(2), dim3(1024), 0, stream>>>(candPoly, candSc, candValid,
                                                  sPoly, sSc, sValid, sAABB);
  pairs_kernel<<<dim3((NW * (NW + 1)) / 2, 2), dim3(256), 0, stream>>>(sValid, sAABB, MT,
                                                                       pairList, pairCount);
  clip_kernel<<<dim3(512), dim3(256), 0, stream>>>(pairList, pairCount, sPoly, MT);
  nms_resolve_emit_kernel<<<dim3(2), dim3(1024), 0, stream>>>(MT, sValid, sPoly, sSc,
                                                              (float*)d_out);
}